// Round 11
// baseline (260.126 us; speedup 1.0000x reference)
//
#include <hip/hip_runtime.h>
#include <stdint.h>

typedef float f32x4 __attribute__((ext_vector_type(4)));
typedef __bf16 bf16x8 __attribute__((ext_vector_type(8)));
typedef unsigned short u16x8 __attribute__((ext_vector_type(8)));

// problem sizes
#define NIMG 32
#define CIN  256
#define HWIN 3136      // 56*56
#define COUT 256
#define HWOUT 2916     // 54*54
#define NPOS 93312     // 32*2916 = 729*128

// workspace layout
#define XT_BYTES   ((size_t)NIMG*HWIN*CIN*2)            // 51,380,224
#define WT_OFF     (XT_BYTES + 8192)
#define WT_BYTES   ((size_t)36*256*64*2)                // 1,179,648
#define WS_NEED    (WT_OFF + WT_BYTES)

static __device__ __forceinline__ unsigned short f2bf(float f) {
    union { float f; uint32_t u; } v; v.f = f;
    return (unsigned short)((v.u + 0x7FFFu + ((v.u >> 16) & 1u)) >> 16);
}

static __device__ __forceinline__ void gload16(const void* g, void* l) {
    __builtin_amdgcn_global_load_lds(
        (const __attribute__((address_space(1))) void*)g,
        (__attribute__((address_space(3))) void*)l, 16, 0, 0);
}

static __device__ __forceinline__ uint32_t lds_a(const void* p) {
    return (uint32_t)(uintptr_t)(__attribute__((address_space(3))) const void*)p;
}

static __device__ __forceinline__ u16x8 ldsr(uint32_t addr) {
    u16x8 r;
    asm volatile("ds_read_b128 %0, %1" : "=v"(r) : "v"(addr));
    return r;
}

#define BAR()   __builtin_amdgcn_s_barrier()
#define SCB()   __builtin_amdgcn_sched_barrier(0)
#define LGKM0() do { asm volatile("s_waitcnt lgkmcnt(0)" ::: "memory"); SCB(); } while (0)
#define VM0()   do { asm volatile("s_waitcnt vmcnt(0)" ::: "memory"); SCB(); } while (0)
#define PRIO1() __builtin_amdgcn_s_setprio(1)
#define PRIO0() __builtin_amdgcn_s_setprio(0)

#define MF(a_, b_, c_) __builtin_amdgcn_mfma_f32_16x16x32_bf16( \
    __builtin_bit_cast(bf16x8, a_), __builtin_bit_cast(bf16x8, b_), c_, 0, 0, 0)

// 16 independent MFMA (distinct acc) for one k-half
#define CLUSTER(A0_, A1_, A2_, A3_, B0_, B1_, B2_, B3_) do {                       \
    acc[0][0]=MF(A0_,B0_,acc[0][0]); acc[1][0]=MF(A1_,B0_,acc[1][0]);              \
    acc[2][0]=MF(A2_,B0_,acc[2][0]); acc[3][0]=MF(A3_,B0_,acc[3][0]);              \
    acc[0][1]=MF(A0_,B1_,acc[0][1]); acc[1][1]=MF(A1_,B1_,acc[1][1]);              \
    acc[2][1]=MF(A2_,B1_,acc[2][1]); acc[3][1]=MF(A3_,B1_,acc[3][1]);              \
    acc[0][2]=MF(A0_,B2_,acc[0][2]); acc[1][2]=MF(A1_,B2_,acc[1][2]);              \
    acc[2][2]=MF(A2_,B2_,acc[2][2]); acc[3][2]=MF(A3_,B2_,acc[3][2]);              \
    acc[0][3]=MF(A0_,B3_,acc[0][3]); acc[1][3]=MF(A1_,B3_,acc[1][3]);              \
    acc[2][3]=MF(A2_,B3_,acc[2][3]); acc[3][3]=MF(A3_,B3_,acc[3][3]);              \
} while (0)

// A-frag direct global loads via INLINE ASM (invisible to compiler waitcnt
// tracking -> no conservative drains; our per-tile VM0 certifies them).
// Layout [kt][256 o][64 c]: row stride 128B, m*16 rows = +2048B, +32c = +64B.
// AN{2m}=(m,half0), AN{2m+1}=(m,half1); canonical k = lg*8+j on both A and B.
#define LOADA(AN, kt_) do {                                                        \
    const char* _p0 = pA_lo + (uint32_t)(kt_) * 32768u;                            \
    const char* _p1 = _p0 + 4096;                                                  \
    asm volatile("global_load_dwordx4 %0, %1, off"             : "=v"(AN##0) : "v"(_p0)); \
    asm volatile("global_load_dwordx4 %0, %1, off offset:64"   : "=v"(AN##1) : "v"(_p0)); \
    asm volatile("global_load_dwordx4 %0, %1, off offset:2048" : "=v"(AN##2) : "v"(_p0)); \
    asm volatile("global_load_dwordx4 %0, %1, off offset:2112" : "=v"(AN##3) : "v"(_p0)); \
    asm volatile("global_load_dwordx4 %0, %1, off"             : "=v"(AN##4) : "v"(_p1)); \
    asm volatile("global_load_dwordx4 %0, %1, off offset:64"   : "=v"(AN##5) : "v"(_p1)); \
    asm volatile("global_load_dwordx4 %0, %1, off offset:2048" : "=v"(AN##6) : "v"(_p1)); \
    asm volatile("global_load_dwordx4 %0, %1, off offset:2112" : "=v"(AN##7) : "v"(_p1)); \
} while (0)

// ---- W transform: [o][c][3][3] f32 -> bf16 +-1, blocked [kt=k9*4+cc][256 o][64 c]
__global__ void wxform(const float* __restrict__ W, unsigned short* __restrict__ Wt) {
    int idx = blockIdx.x * 256 + threadIdx.x;   // 589824 total
    int c6 = idx & 63;
    int o  = (idx >> 6) & 255;
    int cc = (idx >> 14) & 3;
    int k9 = idx >> 16;
    int c = cc * 64 + c6;
    float w = W[(size_t)(o * 256 + c) * 9 + k9];
    Wt[idx] = (w >= 0.0f) ? (unsigned short)0x3F80 : (unsigned short)0xBF80;
}

// ---- X transform: [n][c][56][56] f32 -> [n][hw][c] bf16 (NHWC)
__global__ void xxform(const float* __restrict__ X, unsigned short* __restrict__ Xt) {
    __shared__ float tile[32][65];
    int bid = blockIdx.x;
    int hwc = bid % 49;
    int cc  = (bid / 49) & 7;
    int n   = bid / (49 * 8);
    int hw0 = hwc * 64;
    int c0  = cc * 32;
    int t = threadIdx.x;
    {
        int c = t >> 3;
        int w = (t & 7) * 8;
        const float* src = X + (size_t)(n * CIN + c0 + c) * HWIN + hw0 + w;
        float4 a = *(const float4*)src;
        float4 b = *(const float4*)(src + 4);
        tile[c][w + 0] = a.x; tile[c][w + 1] = a.y; tile[c][w + 2] = a.z; tile[c][w + 3] = a.w;
        tile[c][w + 4] = b.x; tile[c][w + 5] = b.y; tile[c][w + 6] = b.z; tile[c][w + 7] = b.w;
    }
    __syncthreads();
    {
        int w  = t >> 2;
        int cb = (t & 3) * 8;
        u16x8 v;
        #pragma unroll
        for (int j = 0; j < 8; ++j) v[j] = f2bf(tile[cb + j][w]);
        *(u16x8*)(Xt + (size_t)(n * HWIN + hw0 + w) * 256 + c0 + cb) = v;
    }
}

// ---- implicit GEMM: out[o][P] = sum_k Wb[o][k] * X[P][k]
// BM=128 (o), BN=128 (pos), BK=64; 256 thr = 4 waves (2M x 2N), wave tile 64x64
// A: direct global->VGPR inline-asm dwordx4 (Wt L2-resident, dbuf AE/AO, 1-tile
//    prefetch certified by the per-tile VM0); B: LDS dbuf 2x16KB, XOR swizzle
// 2 blocks/CU (bounds(256,2): 256-VGPR budget, no spill)
__global__ __launch_bounds__(256, 2)
void bconv_gemm(const unsigned short* __restrict__ Xt,
                const unsigned short* __restrict__ Wt,
                float* __restrict__ out) {
    __shared__ __align__(16) char smem[32768];

    const int t    = threadIdx.x;
    const int wid  = t >> 6;
    const int lane = t & 63;
    const int l15  = lane & 15;
    const int lg   = lane >> 4;
    const int wr   = wid >> 1;       // 0..1 (M)
    const int wc   = wid & 1;        // 0..1 (N)

    // XCD-bijective swizzle over 1458 blocks (q=182, r=2)
    const uint32_t bid = blockIdx.x;
    const uint32_t xcd = bid & 7u;
    const uint32_t j8  = bid >> 3;
    const uint32_t swz = (xcd < 2u ? xcd * 183u : 366u + (xcd - 2u) * 182u) + j8;
    const int      ob  = (int)(swz & 1u);
    const uint32_t P0  = (swz >> 1) * 128u;

    // B staging constants (XOR swizzle baked into the GLOBAL source column)
    const uint32_t colxB = (uint32_t)(((t & 7) ^ ((t >> 3) & 7)) << 4);  // bytes
    const uint32_t rowt  = (uint32_t)(t >> 3);                           // 0..31

    // A per-lane global base: row (ob*128 + wr*64 + l15), col lg*16 bytes
    const char* pA_lo = (const char*)Wt + (size_t)(ob * 128 + wr * 64 + l15) * 128 + lg * 16;

    // B gather byte bases: 4 rows per thread (r*32 + rowt)
    const char* bB[4];
    #pragma unroll
    for (int r = 0; r < 4; ++r) {
        uint32_t pos = P0 + (uint32_t)(r * 32) + rowt;
        uint32_t ni = pos / (uint32_t)HWOUT;
        uint32_t rm = pos - ni * HWOUT;
        uint32_t ph = rm / 54u;
        uint32_t pw = rm - ph * 54u;
        bB[r] = (const char*)Xt + (size_t)(ni * HWIN + ph * 56u + pw) * 512 + colxB;
    }

    // ds_read offsets (swizzled read side; cancels the staged source swizzle)
    const uint32_t x7  = (uint32_t)(l15 & 7);
    const uint32_t ck0 = ((((uint32_t)lg) ^ x7) << 4);
    const uint32_t ck1 = (((4u | (uint32_t)lg) ^ x7) << 4);
    const uint32_t br0 = (uint32_t)(wc * 64 + 0 * 16 + l15) * 128u;
    const uint32_t br1 = (uint32_t)(wc * 64 + 1 * 16 + l15) * 128u;
    const uint32_t br2 = (uint32_t)(wc * 64 + 2 * 16 + l15) * 128u;
    const uint32_t br3 = (uint32_t)(wc * 64 + 3 * 16 + l15) * 128u;

    const uint32_t E = lds_a(smem);
    const uint32_t O = E + 16384u;

    f32x4 acc[4][4];
    #pragma unroll
    for (int m = 0; m < 4; ++m)
        #pragma unroll
        for (int n = 0; n < 4; ++n)
            acc[m][n] = (f32x4){0.f, 0.f, 0.f, 0.f};

    auto STAGEB = [&](uint32_t bufoff, uint32_t kof) {
        #pragma unroll
        for (int r = 0; r < 4; ++r)
            gload16(bB[r] + kof, smem + bufoff + r * 4096 + (size_t)t * 16);
    };

    // k-offset tracker for tile kt+2: koff = khw*512 + cc*128
    uint32_t cc2 = 2, k32 = 0, koff2 = 256;

    u16x8 AE0, AE1, AE2, AE3, AE4, AE5, AE6, AE7;
    u16x8 AO0, AO1, AO2, AO3, AO4, AO5, AO6, AO7;
    u16x8 U0, U1, U2, U3, V0, V1, V2, V3;

    // prologue: B tiles 0 -> E, 1 -> O; A(0) -> AE, A(1) -> AO; certify all
    STAGEB(0u, 0u);
    STAGEB(16384u, 128u);
    LOADA(AE, 0);
    LOADA(AO, 1);
    VM0();
    BAR();
    SCB();
    U0 = ldsr(E + br0 + ck0); U1 = ldsr(E + br1 + ck0);
    U2 = ldsr(E + br2 + ck0); U3 = ldsr(E + br3 + ck0);
    LGKM0();

// one K-tile: half0 cluster (A even frags x U), half1 cluster (A odd frags x V);
// stage B(kt+2) after the barrier; prefetch A(kt+2) at the tail (ride VMEM queue,
// certified by next GITER's VM0)
#define GITER(kt_, CUR, NXT, CUROFF, AC, F_ST, F_CONT) do {                  \
    V0 = ldsr((CUR) + br0 + ck1); V1 = ldsr((CUR) + br1 + ck1);              \
    V2 = ldsr((CUR) + br2 + ck1); V3 = ldsr((CUR) + br3 + ck1);              \
    SCB();                                                                   \
    PRIO1(); CLUSTER(AC##0, AC##2, AC##4, AC##6, U0, U1, U2, U3); PRIO0();   \
    LGKM0();    /* V ready; all my reads of CUR drained */                   \
    VM0();      /* stage(kt+1)+A(kt+1) retired (issued 1 tile ago) */        \
    BAR(); SCB();                                                            \
    if (F_ST) {                                                              \
        STAGEB(CUROFF, koff2);                                               \
        if (cc2 == 3) { cc2 = 0;                                             \
            koff2 += ((k32 == 2) ? 54u : 1u) * 512u - 384u;                  \
            k32 = (k32 == 2) ? 0u : k32 + 1u; }                              \
        else { cc2++; koff2 += 128u; }                                       \
    }                                                                        \
    if (F_CONT) {                                                            \
        U0 = ldsr((NXT) + br0 + ck0); U1 = ldsr((NXT) + br1 + ck0);          \
        U2 = ldsr((NXT) + br2 + ck0); U3 = ldsr((NXT) + br3 + ck0);          \
        SCB();                                                               \
    }                                                                        \
    PRIO1(); CLUSTER(AC##1, AC##3, AC##5, AC##7, V0, V1, V2, V3); PRIO0();   \
    if (F_ST) { LOADA(AC, (kt_) + 2); }                                      \
    if (F_CONT) { LGKM0(); }                                                 \
} while (0)

    for (int g = 0; g < 17; ++g) {      // kt = 0..33, stages tiles 2..35
        GITER(2 * g,     E, O, 0u,      AE, 1, 1);
        GITER(2 * g + 1, O, E, 16384u,  AO, 1, 1);
    }
    GITER(34, E, O, 0u,     AE, 0, 1);
    GITER(35, O, E, 16384u, AO, 0, 0);

#undef GITER

    // epilogue: C/D col = l15 -> P, row = lg*4+r -> o   (93312 = 729*128 exact)
    const int orow0 = ob * 128 + wr * 64;
    #pragma unroll
    for (int n = 0; n < 4; ++n) {
        uint32_t P = P0 + (uint32_t)(wc * 64 + n * 16 + l15);
        uint32_t ni = P / (uint32_t)HWOUT;
        uint32_t rm = P - ni * HWOUT;
        float* ob_ = out + (size_t)(ni * 256u + orow0) * HWOUT + rm;
        #pragma unroll
        for (int m = 0; m < 4; ++m)
            #pragma unroll
            for (int r = 0; r < 4; ++r)
                ob_[(size_t)(m * 16 + lg * 4 + r) * HWOUT] = acc[m][n][r];
    }
}

// ---- slow correct fallback (only if ws too small)
__global__ void bconv_fallback(const float* __restrict__ X, const float* __restrict__ W,
                               float* __restrict__ out) {
    size_t idx = (size_t)blockIdx.x * 256 + threadIdx.x;
    int ow = (int)(idx % 54);
    int oh = (int)((idx / 54) % 54);
    int o  = (int)((idx / 2916) % 256);
    int n  = (int)(idx / 746496);
    float s = 0.f;
    for (int c = 0; c < 256; ++c) {
        const float* xr = X + ((size_t)(n * 256 + c) * 56 + oh) * 56 + ow;
        const float* wr = W + (size_t)(o * 256 + c) * 9;
        #pragma unroll
        for (int kh = 0; kh < 3; ++kh)
            #pragma unroll
            for (int kw = 0; kw < 3; ++kw) {
                float w = wr[kh * 3 + kw];
                float x = xr[kh * 56 + kw];
                s += (w >= 0.f) ? x : -x;
            }
    }
    out[idx] = s;
}

extern "C" void kernel_launch(void* const* d_in, const int* in_sizes, int n_in,
                              void* d_out, int out_size, void* d_ws, size_t ws_size,
                              hipStream_t stream) {
    const float* X = (const float*)d_in[0];
    const float* W = (const float*)d_in[1];
    float* out = (float*)d_out;

    if (ws_size < WS_NEED) {
        bconv_fallback<<<93312, 256, 0, stream>>>(X, W, out);
        return;
    }
    unsigned short* Xt = (unsigned short*)d_ws;
    unsigned short* Wt = (unsigned short*)((char*)d_ws + WT_OFF);

    wxform<<<2304, 256, 0, stream>>>(W, Wt);
    xxform<<<12544, 256, 0, stream>>>(X, Xt);

    bconv_gemm<<<1458, 256, 0, stream>>>(Xt, Wt, out);
}

// Round 12
// 143.746 us; speedup vs baseline: 1.8096x; 1.8096x over previous
//
#include <hip/hip_runtime.h>
#include <stdint.h>

typedef float f32x4 __attribute__((ext_vector_type(4)));
typedef __bf16 bf16x8 __attribute__((ext_vector_type(8)));
typedef unsigned short u16x8 __attribute__((ext_vector_type(8)));
typedef uint32_t u32x4 __attribute__((ext_vector_type(4)));

// problem sizes
#define NIMG 32
#define CIN  256
#define HWIN 3136      // 56*56
#define COUT 256
#define HWOUT 2916     // 54*54
#define NPOS 93312     // 32*2916 = 729*128

// workspace layout
#define XT_BYTES   ((size_t)NIMG*HWIN*CIN*2)            // 51,380,224
#define WB_OFF     (XT_BYTES + 8192)
#define WB_BYTES   ((size_t)36*4*64*64)                 // 589,824 byte-sign table
#define WS_NEED    (WB_OFF + WB_BYTES)

static __device__ __forceinline__ unsigned short f2bf(float f) {
    union { float f; uint32_t u; } v; v.f = f;
    return (unsigned short)((v.u + 0x7FFFu + ((v.u >> 16) & 1u)) >> 16);
}

static __device__ __forceinline__ void gload16(const void* g, void* l) {
    __builtin_amdgcn_global_load_lds(
        (const __attribute__((address_space(1))) void*)g,
        (__attribute__((address_space(3))) void*)l, 16, 0, 0);
}

static __device__ __forceinline__ uint32_t lds_a(const void* p) {
    return (uint32_t)(uintptr_t)(__attribute__((address_space(3))) const void*)p;
}

static __device__ __forceinline__ u16x8 ldsr(uint32_t addr) {
    u16x8 r;
    asm volatile("ds_read_b128 %0, %1" : "=v"(r) : "v"(addr));
    return r;
}

#define BAR()   __builtin_amdgcn_s_barrier()
#define SCB()   __builtin_amdgcn_sched_barrier(0)
#define LGKM0() do { asm volatile("s_waitcnt lgkmcnt(0)" ::: "memory"); SCB(); } while (0)
#define VM0()   do { asm volatile("s_waitcnt vmcnt(0)" ::: "memory"); SCB(); } while (0)
#define VMC4()  do { asm volatile("s_waitcnt vmcnt(4)" ::: "memory"); SCB(); } while (0)
#define PRIO1() __builtin_amdgcn_s_setprio(1)
#define PRIO0() __builtin_amdgcn_s_setprio(0)

#define MF(a_, b_, c_) __builtin_amdgcn_mfma_f32_16x16x32_bf16( \
    __builtin_bit_cast(bf16x8, a_), __builtin_bit_cast(bf16x8, b_), c_, 0, 0, 0)

// 16 independent MFMA (distinct acc) for one k-half
#define CLUSTER(A0_, A1_, A2_, A3_, B0_, B1_, B2_, B3_) do {                       \
    acc[0][0]=MF(A0_,B0_,acc[0][0]); acc[1][0]=MF(A1_,B0_,acc[1][0]);              \
    acc[2][0]=MF(A2_,B0_,acc[2][0]); acc[3][0]=MF(A3_,B0_,acc[3][0]);              \
    acc[0][1]=MF(A0_,B1_,acc[0][1]); acc[1][1]=MF(A1_,B1_,acc[1][1]);              \
    acc[2][1]=MF(A2_,B1_,acc[2][1]); acc[3][1]=MF(A3_,B1_,acc[3][1]);              \
    acc[0][2]=MF(A0_,B2_,acc[0][2]); acc[1][2]=MF(A1_,B2_,acc[1][2]);              \
    acc[2][2]=MF(A2_,B2_,acc[2][2]); acc[3][2]=MF(A3_,B2_,acc[3][2]);              \
    acc[0][3]=MF(A0_,B3_,acc[0][3]); acc[1][3]=MF(A1_,B3_,acc[1][3]);              \
    acc[2][3]=MF(A2_,B3_,acc[2][3]); acc[3][3]=MF(A3_,B3_,acc[3][3]);              \
} while (0)

// byte-signs -> bf16 +-1 frags: per dword 1 v_perm (signs into hi-byte slots,
// zeros elsewhere) + 1 v_or 0x3F803F80. QA_ = dwords (frag m0: j0-7, m1),
// QB_ = (m2, m3). sel 0x0C = const 0x00; same-reg perm so selector&3 picks byte.
#define EXPH(D0_, D1_, D2_, D3_, QA_, QB_) do {                                     \
    union { uint32_t d[4]; u16x8 v; } _e0, _e1, _e2, _e3;                           \
    _e0.d[0] = 0x3F803F80u | __builtin_amdgcn_perm(QA_[0], QA_[0], 0x010C000Cu);    \
    _e0.d[1] = 0x3F803F80u | __builtin_amdgcn_perm(QA_[0], QA_[0], 0x030C020Cu);    \
    _e0.d[2] = 0x3F803F80u | __builtin_amdgcn_perm(QA_[1], QA_[1], 0x010C000Cu);    \
    _e0.d[3] = 0x3F803F80u | __builtin_amdgcn_perm(QA_[1], QA_[1], 0x030C020Cu);    \
    _e1.d[0] = 0x3F803F80u | __builtin_amdgcn_perm(QA_[2], QA_[2], 0x010C000Cu);    \
    _e1.d[1] = 0x3F803F80u | __builtin_amdgcn_perm(QA_[2], QA_[2], 0x030C020Cu);    \
    _e1.d[2] = 0x3F803F80u | __builtin_amdgcn_perm(QA_[3], QA_[3], 0x010C000Cu);    \
    _e1.d[3] = 0x3F803F80u | __builtin_amdgcn_perm(QA_[3], QA_[3], 0x030C020Cu);    \
    _e2.d[0] = 0x3F803F80u | __builtin_amdgcn_perm(QB_[0], QB_[0], 0x010C000Cu);    \
    _e2.d[1] = 0x3F803F80u | __builtin_amdgcn_perm(QB_[0], QB_[0], 0x030C020Cu);    \
    _e2.d[2] = 0x3F803F80u | __builtin_amdgcn_perm(QB_[1], QB_[1], 0x010C000Cu);    \
    _e2.d[3] = 0x3F803F80u | __builtin_amdgcn_perm(QB_[1], QB_[1], 0x030C020Cu);    \
    _e3.d[0] = 0x3F803F80u | __builtin_amdgcn_perm(QB_[2], QB_[2], 0x010C000Cu);    \
    _e3.d[1] = 0x3F803F80u | __builtin_amdgcn_perm(QB_[2], QB_[2], 0x030C020Cu);    \
    _e3.d[2] = 0x3F803F80u | __builtin_amdgcn_perm(QB_[3], QB_[3], 0x010C000Cu);    \
    _e3.d[3] = 0x3F803F80u | __builtin_amdgcn_perm(QB_[3], QB_[3], 0x030C020Cu);    \
    D0_ = _e0.v; D1_ = _e1.v; D2_ = _e2.v; D3_ = _e3.v;                             \
} while (0)

// sign-byte loads: 4 asm dwordx4 (64B/lane/tile); invisible to compiler waitcnt;
// certified by the counted vmcnt in the schedule
#define SLOAD(QN, kt_) do {                                                         \
    const char* _p = pWb + (uint32_t)(kt_) * 16384u;                                \
    asm volatile("global_load_dwordx4 %0, %1, off"           : "=v"(QN##0) : "v"(_p)); \
    asm volatile("global_load_dwordx4 %0, %1, off offset:16" : "=v"(QN##1) : "v"(_p)); \
    asm volatile("global_load_dwordx4 %0, %1, off offset:32" : "=v"(QN##2) : "v"(_p)); \
    asm volatile("global_load_dwordx4 %0, %1, off offset:48" : "=v"(QN##3) : "v"(_p)); \
} while (0)

// ---- W byte-sign transform: lane-slot byte b = h*32 + m*8 + j holds 0x80 iff
// W[o][c][k9] < 0, o = ob*128+wr*64+m*16+l15, c = (kt&3)*64 + lg*8 + h*32 + j
__global__ void wbits_k(const float* __restrict__ W, uint32_t* __restrict__ Wb) {
    int kt = blockIdx.x;
    int t  = threadIdx.x;
    int lane = t & 63;
    int wr   = (t >> 6) & 1;
    int ob   = t >> 7;
    int l15 = lane & 15, lg = lane >> 4;
    int k9 = kt >> 2;
    int cb = (kt & 3) * 64 + lg * 8;
    int obase = ob * 128 + wr * 64 + l15;
    uint32_t d[16];
    #pragma unroll
    for (int i = 0; i < 16; ++i) d[i] = 0;
    #pragma unroll
    for (int h = 0; h < 2; ++h)
        #pragma unroll
        for (int m = 0; m < 4; ++m)
            #pragma unroll
            for (int j = 0; j < 8; ++j) {
                float w = W[((size_t)(obase + m * 16) * 256 + (cb + h * 32 + j)) * 9 + k9];
                if (w < 0.0f) d[h * 8 + m * 2 + (j >> 2)] |= 0x80u << ((j & 3) * 8);
            }
    uint32_t* dst = Wb + ((size_t)((kt * 4 + ob * 2 + wr) * 64 + lane)) * 16;
    #pragma unroll
    for (int q = 0; q < 4; ++q)
        *(u32x4*)(dst + q * 4) = (u32x4){d[q*4+0], d[q*4+1], d[q*4+2], d[q*4+3]};
}

// ---- X transform: [n][c][56][56] f32 -> [n][hw][c] bf16 (NHWC)
__global__ void xxform(const float* __restrict__ X, unsigned short* __restrict__ Xt) {
    __shared__ float tile[32][65];
    int bid = blockIdx.x;
    int hwc = bid % 49;
    int cc  = (bid / 49) & 7;
    int n   = bid / (49 * 8);
    int hw0 = hwc * 64;
    int c0  = cc * 32;
    int t = threadIdx.x;
    {
        int c = t >> 3;
        int w = (t & 7) * 8;
        const float* src = X + (size_t)(n * CIN + c0 + c) * HWIN + hw0 + w;
        float4 a = *(const float4*)src;
        float4 b = *(const float4*)(src + 4);
        tile[c][w + 0] = a.x; tile[c][w + 1] = a.y; tile[c][w + 2] = a.z; tile[c][w + 3] = a.w;
        tile[c][w + 4] = b.x; tile[c][w + 5] = b.y; tile[c][w + 6] = b.z; tile[c][w + 7] = b.w;
    }
    __syncthreads();
    {
        int w  = t >> 2;
        int cb = (t & 3) * 8;
        u16x8 v;
        #pragma unroll
        for (int j = 0; j < 8; ++j) v[j] = f2bf(tile[cb + j][w]);
        *(u16x8*)(Xt + (size_t)(n * HWIN + hw0 + w) * 256 + c0 + cb) = v;
    }
}

// ---- bit-A implicit GEMM (R10 skeleton + perm-expansion + counted vmcnt):
// BM=128, BN=128, BK=64; 256 thr = 4 waves (2Mx2N), wave tile 64x64; B LDS dbuf
// 2x16KB XOR-swizzled; A = byte-sign table -> v_perm expansion, pipelined one
// half-cluster ahead of its consuming MFMA cluster; 2 blocks/CU
__global__ __launch_bounds__(256, 2)
void bconv_gemm(const unsigned short* __restrict__ Xt,
                const char* __restrict__ Wb,
                float* __restrict__ out) {
    __shared__ __align__(16) char smem[32768];

    const int t    = threadIdx.x;
    const int wid  = t >> 6;
    const int lane = t & 63;
    const int l15  = lane & 15;
    const int lg   = lane >> 4;
    const int wr   = wid >> 1;       // 0..1 (M)
    const int wc   = wid & 1;        // 0..1 (N)

    // XCD-bijective swizzle over 1458 blocks (q=182, r=2)
    const uint32_t bid = blockIdx.x;
    const uint32_t xcd = bid & 7u;
    const uint32_t j8  = bid >> 3;
    const uint32_t swz = (xcd < 2u ? xcd * 183u : 366u + (xcd - 2u) * 182u) + j8;
    const int      ob  = (int)(swz & 1u);
    const uint32_t P0  = (swz >> 1) * 128u;

    // B staging constants (XOR swizzle baked into the GLOBAL source column)
    const uint32_t colxB = (uint32_t)(((t & 7) ^ ((t >> 3) & 7)) << 4);  // bytes
    const uint32_t rowt  = (uint32_t)(t >> 3);                           // 0..31

    // sign-table base for this wave's (ob, wr) slot
    const char* pWb = Wb + ((size_t)((ob * 2 + wr) * 64 + lane)) * 64;

    // B gather byte bases: 4 rows per thread (r*32 + rowt)
    const char* bB[4];
    #pragma unroll
    for (int r = 0; r < 4; ++r) {
        uint32_t pos = P0 + (uint32_t)(r * 32) + rowt;
        uint32_t ni = pos / (uint32_t)HWOUT;
        uint32_t rm = pos - ni * HWOUT;
        uint32_t ph = rm / 54u;
        uint32_t pw = rm - ph * 54u;
        bB[r] = (const char*)Xt + (size_t)(ni * HWIN + ph * 56u + pw) * 512 + colxB;
    }

    // ds_read offsets (swizzled read side; cancels the staged source swizzle)
    const uint32_t x7  = (uint32_t)(l15 & 7);
    const uint32_t ck0 = ((((uint32_t)lg) ^ x7) << 4);
    const uint32_t ck1 = (((4u | (uint32_t)lg) ^ x7) << 4);
    const uint32_t br0 = (uint32_t)(wc * 64 + 0 * 16 + l15) * 128u;
    const uint32_t br1 = (uint32_t)(wc * 64 + 1 * 16 + l15) * 128u;
    const uint32_t br2 = (uint32_t)(wc * 64 + 2 * 16 + l15) * 128u;
    const uint32_t br3 = (uint32_t)(wc * 64 + 3 * 16 + l15) * 128u;

    const uint32_t E = lds_a(smem);
    const uint32_t O = E + 16384u;

    f32x4 acc[4][4];
    #pragma unroll
    for (int m = 0; m < 4; ++m)
        #pragma unroll
        for (int n = 0; n < 4; ++n)
            acc[m][n] = (f32x4){0.f, 0.f, 0.f, 0.f};

    auto STAGEB = [&](uint32_t bufoff, uint32_t kof) {
        #pragma unroll
        for (int r = 0; r < 4; ++r)
            gload16(bB[r] + kof, smem + bufoff + r * 4096 + (size_t)t * 16);
    };

    // k-offset tracker for tile kt+2: koff = khw*512 + cc*128
    uint32_t cc2 = 2, k32 = 0, koff2 = 256;

    u32x4 SE0, SE1, SE2, SE3, SO0, SO1, SO2, SO3;
    u16x8 a0, a1, a2, a3;       // A frags for half0 cluster
    u16x8 c0, c1, c2, c3;       // A frags for half1 cluster
    u16x8 U0, U1, U2, U3, V0, V1, V2, V3;

    // prologue: B tiles 0 -> E, 1 -> O; signs(0) -> SE; certify; expand a(0,h0)
    STAGEB(0u, 0u);
    STAGEB(16384u, 128u);
    SLOAD(SE, 0);
    VM0();
    BAR();
    SCB();
    U0 = ldsr(E + br0 + ck0); U1 = ldsr(E + br1 + ck0);
    U2 = ldsr(E + br2 + ck0); U3 = ldsr(E + br3 + ck0);
    LGKM0();
    EXPH(a0, a1, a2, a3, SE0, SE1);

// One K-tile. VMEM queue (in-order): at f, [stage(kt+1):4, signs(kt+1):4] ->
// vmcnt(4) certifies stage without draining signs; at j, [signs(kt+1):4,
// stage(kt+2):4] -> vmcnt(4) certifies signs. Expansion always >=1 cluster
// ahead of its consumer.
#define GITER(kt_, CUR, NXT, CUROFF, SC, SN, F_LA, F_ST, F_CONT) do {        \
    V0 = ldsr((CUR) + br0 + ck1); V1 = ldsr((CUR) + br1 + ck1);              \
    V2 = ldsr((CUR) + br2 + ck1); V3 = ldsr((CUR) + br3 + ck1);              \
    if (F_LA) { SLOAD(SN, (kt_) + 1); }                                      \
    EXPH(c0, c1, c2, c3, SC##2, SC##3);                                      \
    SCB();                                                                   \
    PRIO1(); CLUSTER(a0, a1, a2, a3, U0, U1, U2, U3); PRIO0();               \
    LGKM0();    /* V ready; all my reads of CUR drained */                   \
    if (F_CONT) {                                                            \
        VMC4();     /* stage(kt+1) done (oldest 4); signs stay in flight */  \
        BAR(); SCB();                                                        \
        if (F_ST) {                                                          \
            STAGEB(CUROFF, koff2);                                           \
            if (cc2 == 3) { cc2 = 0;                                         \
                koff2 += ((k32 == 2) ? 54u : 1u) * 512u - 384u;              \
                k32 = (k32 == 2) ? 0u : k32 + 1u; }                          \
            else { cc2++; koff2 += 128u; }                                   \
        }                                                                    \
        U0 = ldsr((NXT) + br0 + ck0); U1 = ldsr((NXT) + br1 + ck0);          \
        U2 = ldsr((NXT) + br2 + ck0); U3 = ldsr((NXT) + br3 + ck0);          \
        if (F_ST) { VMC4(); } else { VM0(); }  /* signs(kt+1) ready */       \
        EXPH(a0, a1, a2, a3, SN##0, SN##1);                                  \
        SCB();                                                               \
    }                                                                        \
    PRIO1(); CLUSTER(c0, c1, c2, c3, V0, V1, V2, V3); PRIO0();               \
    if (F_CONT) { LGKM0(); }                                                 \
} while (0)

    for (int g = 0; g < 17; ++g) {      // kt = 0..33, stages tiles 2..35
        GITER(2 * g,     E, O, 0u,      SE, SO, 1, 1, 1);
        GITER(2 * g + 1, O, E, 16384u,  SO, SE, 1, 1, 1);
    }
    GITER(34, E, O, 0u,     SE, SO, 1, 0, 1);
    GITER(35, O, E, 16384u, SO, SE, 0, 0, 0);

#undef GITER

    // epilogue: C/D col = l15 -> P, row = lg*4+r -> o   (93312 = 729*128 exact)
    const int orow0 = ob * 128 + wr * 64;
    #pragma unroll
    for (int n = 0; n < 4; ++n) {
        uint32_t P = P0 + (uint32_t)(wc * 64 + n * 16 + l15);
        uint32_t ni = P / (uint32_t)HWOUT;
        uint32_t rm = P - ni * HWOUT;
        float* ob_ = out + (size_t)(ni * 256u + orow0) * HWOUT + rm;
        #pragma unroll
        for (int m = 0; m < 4; ++m)
            #pragma unroll
            for (int r = 0; r < 4; ++r)
                ob_[(size_t)(m * 16 + lg * 4 + r) * HWOUT] = acc[m][n][r];
    }
}

// ---- slow correct fallback (only if ws too small)
__global__ void bconv_fallback(const float* __restrict__ X, const float* __restrict__ W,
                               float* __restrict__ out) {
    size_t idx = (size_t)blockIdx.x * 256 + threadIdx.x;
    int ow = (int)(idx % 54);
    int oh = (int)((idx / 54) % 54);
    int o  = (int)((idx / 2916) % 256);
    int n  = (int)(idx / 746496);
    float s = 0.f;
    for (int c = 0; c < 256; ++c) {
        const float* xr = X + ((size_t)(n * 256 + c) * 56 + oh) * 56 + ow;
        const float* wr = W + (size_t)(o * 256 + c) * 9;
        #pragma unroll
        for (int kh = 0; kh < 3; ++kh)
            #pragma unroll
            for (int kw = 0; kw < 3; ++kw) {
                float w = wr[kh * 3 + kw];
                float x = xr[kh * 56 + kw];
                s += (w >= 0.f) ? x : -x;
            }
    }
    out[idx] = s;
}

extern "C" void kernel_launch(void* const* d_in, const int* in_sizes, int n_in,
                              void* d_out, int out_size, void* d_ws, size_t ws_size,
                              hipStream_t stream) {
    const float* X = (const float*)d_in[0];
    const float* W = (const float*)d_in[1];
    float* out = (float*)d_out;

    if (ws_size < WS_NEED) {
        bconv_fallback<<<93312, 256, 0, stream>>>(X, W, out);
        return;
    }
    unsigned short* Xt = (unsigned short*)d_ws;
    uint32_t* Wb = (uint32_t*)((char*)d_ws + WB_OFF);

    wbits_k<<<36, 256, 0, stream>>>(W, Wb);
    xxform<<<12544, 256, 0, stream>>>(X, Xt);

    bconv_gemm<<<1458, 256, 0, stream>>>(Xt, (const char*)Wb, out);
}

// Round 14
// 139.536 us; speedup vs baseline: 1.8642x; 1.0302x over previous
//
#include <hip/hip_runtime.h>
#include <stdint.h>

typedef float f32x4 __attribute__((ext_vector_type(4)));
typedef __bf16 bf16x8 __attribute__((ext_vector_type(8)));
typedef unsigned short u16x8 __attribute__((ext_vector_type(8)));
typedef uint32_t u32x4 __attribute__((ext_vector_type(4)));

// problem sizes
#define NIMG 32
#define CIN  256
#define HWIN 3136      // 56*56
#define COUT 256
#define HWOUT 2916     // 54*54
#define NPOS 93312     // 32*2916 = 729*128

// workspace layout
#define XT_BYTES   ((size_t)NIMG*HWIN*CIN*2)            // 51,380,224
#define WB_OFF     (XT_BYTES + 8192)
#define WB_BYTES   ((size_t)36*4*64*64)                 // 589,824 byte-sign table
#define WS_NEED    (WB_OFF + WB_BYTES)

static __device__ __forceinline__ unsigned short f2bf(float f) {
    union { float f; uint32_t u; } v; v.f = f;
    return (unsigned short)((v.u + 0x7FFFu + ((v.u >> 16) & 1u)) >> 16);
}

static __device__ __forceinline__ void gload16(const void* g, void* l) {
    __builtin_amdgcn_global_load_lds(
        (const __attribute__((address_space(1))) void*)g,
        (__attribute__((address_space(3))) void*)l, 16, 0, 0);
}

static __device__ __forceinline__ uint32_t lds_a(const void* p) {
    return (uint32_t)(uintptr_t)(__attribute__((address_space(3))) const void*)p;
}

static __device__ __forceinline__ u16x8 ldsr(uint32_t addr) {
    u16x8 r;
    asm volatile("ds_read_b128 %0, %1" : "=v"(r) : "v"(addr));
    return r;
}

#define BAR()   __builtin_amdgcn_s_barrier()
#define SCB()   __builtin_amdgcn_sched_barrier(0)
#define LGKM0() do { asm volatile("s_waitcnt lgkmcnt(0)" ::: "memory"); SCB(); } while (0)
#define VM0()   do { asm volatile("s_waitcnt vmcnt(0)" ::: "memory"); SCB(); } while (0)
#define VMC4()  do { asm volatile("s_waitcnt vmcnt(4)" ::: "memory"); SCB(); } while (0)

#define MF(a_, b_, c_) __builtin_amdgcn_mfma_f32_16x16x32_bf16( \
    __builtin_bit_cast(bf16x8, a_), __builtin_bit_cast(bf16x8, b_), c_, 0, 0, 0)

// 16 independent MFMA (distinct acc) for one k-half
#define CLUSTER(A0_, A1_, A2_, A3_, B0_, B1_, B2_, B3_) do {                       \
    acc[0][0]=MF(A0_,B0_,acc[0][0]); acc[1][0]=MF(A1_,B0_,acc[1][0]);              \
    acc[2][0]=MF(A2_,B0_,acc[2][0]); acc[3][0]=MF(A3_,B0_,acc[3][0]);              \
    acc[0][1]=MF(A0_,B1_,acc[0][1]); acc[1][1]=MF(A1_,B1_,acc[1][1]);              \
    acc[2][1]=MF(A2_,B1_,acc[2][1]); acc[3][1]=MF(A3_,B1_,acc[3][1]);              \
    acc[0][2]=MF(A0_,B2_,acc[0][2]); acc[1][2]=MF(A1_,B2_,acc[1][2]);              \
    acc[2][2]=MF(A2_,B2_,acc[2][2]); acc[3][2]=MF(A3_,B2_,acc[3][2]);              \
    acc[0][3]=MF(A0_,B3_,acc[0][3]); acc[1][3]=MF(A1_,B3_,acc[1][3]);              \
    acc[2][3]=MF(A2_,B3_,acc[2][3]); acc[3][3]=MF(A3_,B3_,acc[3][3]);              \
} while (0)

// byte-signs -> bf16 +-1 frags: per dword 1 v_perm (signs into hi-byte slots,
// zeros elsewhere) + 1 v_or 0x3F803F80. QA_ = dwords (frag m0: j0-7, m1),
// QB_ = (m2, m3). sel 0x0C = const 0x00; same-reg perm so selector&3 picks byte.
#define EXPH(D0_, D1_, D2_, D3_, QA_, QB_) do {                                     \
    union { uint32_t d[4]; u16x8 v; } _e0, _e1, _e2, _e3;                           \
    _e0.d[0] = 0x3F803F80u | __builtin_amdgcn_perm(QA_[0], QA_[0], 0x010C000Cu);    \
    _e0.d[1] = 0x3F803F80u | __builtin_amdgcn_perm(QA_[0], QA_[0], 0x030C020Cu);    \
    _e0.d[2] = 0x3F803F80u | __builtin_amdgcn_perm(QA_[1], QA_[1], 0x010C000Cu);    \
    _e0.d[3] = 0x3F803F80u | __builtin_amdgcn_perm(QA_[1], QA_[1], 0x030C020Cu);    \
    _e1.d[0] = 0x3F803F80u | __builtin_amdgcn_perm(QA_[2], QA_[2], 0x010C000Cu);    \
    _e1.d[1] = 0x3F803F80u | __builtin_amdgcn_perm(QA_[2], QA_[2], 0x030C020Cu);    \
    _e1.d[2] = 0x3F803F80u | __builtin_amdgcn_perm(QA_[3], QA_[3], 0x010C000Cu);    \
    _e1.d[3] = 0x3F803F80u | __builtin_amdgcn_perm(QA_[3], QA_[3], 0x030C020Cu);    \
    _e2.d[0] = 0x3F803F80u | __builtin_amdgcn_perm(QB_[0], QB_[0], 0x010C000Cu);    \
    _e2.d[1] = 0x3F803F80u | __builtin_amdgcn_perm(QB_[0], QB_[0], 0x030C020Cu);    \
    _e2.d[2] = 0x3F803F80u | __builtin_amdgcn_perm(QB_[1], QB_[1], 0x010C000Cu);    \
    _e2.d[3] = 0x3F803F80u | __builtin_amdgcn_perm(QB_[1], QB_[1], 0x030C020Cu);    \
    _e3.d[0] = 0x3F803F80u | __builtin_amdgcn_perm(QB_[2], QB_[2], 0x010C000Cu);    \
    _e3.d[1] = 0x3F803F80u | __builtin_amdgcn_perm(QB_[2], QB_[2], 0x030C020Cu);    \
    _e3.d[2] = 0x3F803F80u | __builtin_amdgcn_perm(QB_[3], QB_[3], 0x010C000Cu);    \
    _e3.d[3] = 0x3F803F80u | __builtin_amdgcn_perm(QB_[3], QB_[3], 0x030C020Cu);    \
    D0_ = _e0.v; D1_ = _e1.v; D2_ = _e2.v; D3_ = _e3.v;                             \
} while (0)

// sign-byte loads: 4 asm dwordx4 (64B/lane/tile); invisible to compiler waitcnt;
// certified by the counted vmcnt in the schedule
#define SLOAD(QN, kt_) do {                                                         \
    const char* _p = pWb + (uint32_t)(kt_) * 16384u;                                \
    asm volatile("global_load_dwordx4 %0, %1, off"           : "=v"(QN##0) : "v"(_p)); \
    asm volatile("global_load_dwordx4 %0, %1, off offset:16" : "=v"(QN##1) : "v"(_p)); \
    asm volatile("global_load_dwordx4 %0, %1, off offset:32" : "=v"(QN##2) : "v"(_p)); \
    asm volatile("global_load_dwordx4 %0, %1, off offset:48" : "=v"(QN##3) : "v"(_p)); \
} while (0)

// ---- W byte-sign transform: lane-slot byte b = h*32 + m*8 + j holds 0x80 iff
// W[o][c][k9] < 0, o = ob*128+wr*64+m*16+l15, c = (kt&3)*64 + lg*8 + h*32 + j
__global__ void wbits_k(const float* __restrict__ W, uint32_t* __restrict__ Wb) {
    int kt = blockIdx.x;
    int t  = threadIdx.x;
    int lane = t & 63;
    int wr   = (t >> 6) & 1;
    int ob   = t >> 7;
    int l15 = lane & 15, lg = lane >> 4;
    int k9 = kt >> 2;
    int cb = (kt & 3) * 64 + lg * 8;
    int obase = ob * 128 + wr * 64 + l15;
    uint32_t d[16];
    #pragma unroll
    for (int i = 0; i < 16; ++i) d[i] = 0;
    #pragma unroll
    for (int h = 0; h < 2; ++h)
        #pragma unroll
        for (int m = 0; m < 4; ++m)
            #pragma unroll
            for (int j = 0; j < 8; ++j) {
                float w = W[((size_t)(obase + m * 16) * 256 + (cb + h * 32 + j)) * 9 + k9];
                if (w < 0.0f) d[h * 8 + m * 2 + (j >> 2)] |= 0x80u << ((j & 3) * 8);
            }
    uint32_t* dst = Wb + ((size_t)((kt * 4 + ob * 2 + wr) * 64 + lane)) * 16;
    #pragma unroll
    for (int q = 0; q < 4; ++q)
        *(u32x4*)(dst + q * 4) = (u32x4){d[q*4+0], d[q*4+1], d[q*4+2], d[q*4+3]};
}

// ---- X transform: [n][c][56][56] f32 -> [n][hw][c] bf16 (NHWC)
__global__ void xxform(const float* __restrict__ X, unsigned short* __restrict__ Xt) {
    __shared__ float tile[32][65];
    int bid = blockIdx.x;
    int hwc = bid % 49;
    int cc  = (bid / 49) & 7;
    int n   = bid / (49 * 8);
    int hw0 = hwc * 64;
    int c0  = cc * 32;
    int t = threadIdx.x;
    {
        int c = t >> 3;
        int w = (t & 7) * 8;
        const float* src = X + (size_t)(n * CIN + c0 + c) * HWIN + hw0 + w;
        float4 a = *(const float4*)src;
        float4 b = *(const float4*)(src + 4);
        tile[c][w + 0] = a.x; tile[c][w + 1] = a.y; tile[c][w + 2] = a.z; tile[c][w + 3] = a.w;
        tile[c][w + 4] = b.x; tile[c][w + 5] = b.y; tile[c][w + 6] = b.z; tile[c][w + 7] = b.w;
    }
    __syncthreads();
    {
        int w  = t >> 2;
        int cb = (t & 3) * 8;
        u16x8 v;
        #pragma unroll
        for (int j = 0; j < 8; ++j) v[j] = f2bf(tile[cb + j][w]);
        *(u16x8*)(Xt + (size_t)(n * HWIN + hw0 + w) * 256 + c0 + cb) = v;
    }
}

// ---- bit-A implicit GEMM (R12 minus interleave-blocking fences):
// BM=128, BN=128, BK=64; 256 thr = 4 waves (2Mx2N), wave tile 64x64; B LDS dbuf
// 2x16KB XOR-swizzled; A = byte-sign table -> v_perm expansion.
// EXPH and CLUSTER share one fence region -> compiler interleaves expansion
// VALU into MFMA issue gaps (R12's SCB between them forbade this).
// Wait-fences (SCB after each waitcnt, rule #18) kept; STAGEB and SLOAD remain
// in distinct fenced regions so counted-vmcnt queue order is preserved.
// bounds(256,2): natural register usage, NO allocator squeeze (R13 lesson).
__global__ __launch_bounds__(256, 2)
void bconv_gemm(const unsigned short* __restrict__ Xt,
                const char* __restrict__ Wb,
                float* __restrict__ out) {
    __shared__ __align__(16) char smem[32768];

    const int t    = threadIdx.x;
    const int wid  = t >> 6;
    const int lane = t & 63;
    const int l15  = lane & 15;
    const int lg   = lane >> 4;
    const int wr   = wid >> 1;       // 0..1 (M)
    const int wc   = wid & 1;        // 0..1 (N)

    // XCD-bijective swizzle over 1458 blocks (q=182, r=2)
    const uint32_t bid = blockIdx.x;
    const uint32_t xcd = bid & 7u;
    const uint32_t j8  = bid >> 3;
    const uint32_t swz = (xcd < 2u ? xcd * 183u : 366u + (xcd - 2u) * 182u) + j8;
    const int      ob  = (int)(swz & 1u);
    const uint32_t P0  = (swz >> 1) * 128u;

    // B staging constants (XOR swizzle baked into the GLOBAL source column)
    const uint32_t colxB = (uint32_t)(((t & 7) ^ ((t >> 3) & 7)) << 4);  // bytes
    const uint32_t rowt  = (uint32_t)(t >> 3);                           // 0..31

    // sign-table base for this wave's (ob, wr) slot
    const char* pWb = Wb + ((size_t)((ob * 2 + wr) * 64 + lane)) * 64;

    // B gather byte bases: 4 rows per thread (r*32 + rowt)
    const char* bB[4];
    #pragma unroll
    for (int r = 0; r < 4; ++r) {
        uint32_t pos = P0 + (uint32_t)(r * 32) + rowt;
        uint32_t ni = pos / (uint32_t)HWOUT;
        uint32_t rm = pos - ni * HWOUT;
        uint32_t ph = rm / 54u;
        uint32_t pw = rm - ph * 54u;
        bB[r] = (const char*)Xt + (size_t)(ni * HWIN + ph * 56u + pw) * 512 + colxB;
    }

    // ds_read offsets (swizzled read side; cancels the staged source swizzle)
    const uint32_t x7  = (uint32_t)(l15 & 7);
    const uint32_t ck0 = ((((uint32_t)lg) ^ x7) << 4);
    const uint32_t ck1 = (((4u | (uint32_t)lg) ^ x7) << 4);
    const uint32_t br0 = (uint32_t)(wc * 64 + 0 * 16 + l15) * 128u;
    const uint32_t br1 = (uint32_t)(wc * 64 + 1 * 16 + l15) * 128u;
    const uint32_t br2 = (uint32_t)(wc * 64 + 2 * 16 + l15) * 128u;
    const uint32_t br3 = (uint32_t)(wc * 64 + 3 * 16 + l15) * 128u;

    const uint32_t E = lds_a(smem);
    const uint32_t O = E + 16384u;

    f32x4 acc[4][4];
    #pragma unroll
    for (int m = 0; m < 4; ++m)
        #pragma unroll
        for (int n = 0; n < 4; ++n)
            acc[m][n] = (f32x4){0.f, 0.f, 0.f, 0.f};

    auto STAGEB = [&](uint32_t bufoff, uint32_t kof) {
        #pragma unroll
        for (int r = 0; r < 4; ++r)
            gload16(bB[r] + kof, smem + bufoff + r * 4096 + (size_t)t * 16);
    };

    // k-offset tracker for tile kt+2: koff = khw*512 + cc*128
    uint32_t cc2 = 2, k32 = 0, koff2 = 256;

    u32x4 SE0, SE1, SE2, SE3, SO0, SO1, SO2, SO3;
    u16x8 a0, a1, a2, a3;       // A frags for half0 cluster
    u16x8 c0, c1, c2, c3;       // A frags for half1 cluster
    u16x8 U0, U1, U2, U3, V0, V1, V2, V3;

    // prologue: B tiles 0 -> E, 1 -> O; signs(0) -> SE; certify; expand a(0,h0)
    STAGEB(0u, 0u);
    STAGEB(16384u, 128u);
    SLOAD(SE, 0);
    VM0();
    BAR();
    SCB();
    U0 = ldsr(E + br0 + ck0); U1 = ldsr(E + br1 + ck0);
    U2 = ldsr(E + br2 + ck0); U3 = ldsr(E + br3 + ck0);
    LGKM0();
    EXPH(a0, a1, a2, a3, SE0, SE1);

// One K-tile. VMEM queue (in-order): at the first counted wait,
// [stage(kt+1):4, signs(kt+1):4] -> vmcnt(4) certifies stage without draining
// signs; at the second, [signs(kt+1):4, stage(kt+2):4] -> vmcnt(4) certifies
// signs. EXPH shares a fence region with its following CLUSTER -> interleave.
#define GITER(kt_, CUR, NXT, CUROFF, SC, SN, F_LA, F_ST, F_CONT) do {        \
    V0 = ldsr((CUR) + br0 + ck1); V1 = ldsr((CUR) + br1 + ck1);              \
    V2 = ldsr((CUR) + br2 + ck1); V3 = ldsr((CUR) + br3 + ck1);              \
    if (F_LA) { SLOAD(SN, (kt_) + 1); }                                      \
    EXPH(c0, c1, c2, c3, SC##2, SC##3);                                      \
    CLUSTER(a0, a1, a2, a3, U0, U1, U2, U3);                                 \
    LGKM0();    /* V ready; all my reads of CUR drained */                   \
    if (F_CONT) {                                                            \
        VMC4();     /* stage(kt+1) done (oldest 4); signs stay in flight */  \
        BAR(); SCB();                                                        \
        if (F_ST) {                                                          \
            STAGEB(CUROFF, koff2);                                           \
            if (cc2 == 3) { cc2 = 0;                                         \
                koff2 += ((k32 == 2) ? 54u : 1u) * 512u - 384u;              \
                k32 = (k32 == 2) ? 0u : k32 + 1u; }                          \
            else { cc2++; koff2 += 128u; }                                   \
        }                                                                    \
        U0 = ldsr((NXT) + br0 + ck0); U1 = ldsr((NXT) + br1 + ck0);          \
        U2 = ldsr((NXT) + br2 + ck0); U3 = ldsr((NXT) + br3 + ck0);          \
        if (F_ST) { VMC4(); } else { VM0(); }  /* signs(kt+1) ready */       \
        EXPH(a0, a1, a2, a3, SN##0, SN##1);                                  \
    }                                                                        \
    CLUSTER(c0, c1, c2, c3, V0, V1, V2, V3);                                 \
    if (F_CONT) { LGKM0(); }                                                 \
} while (0)

    for (int g = 0; g < 17; ++g) {      // kt = 0..33, stages tiles 2..35
        GITER(2 * g,     E, O, 0u,      SE, SO, 1, 1, 1);
        GITER(2 * g + 1, O, E, 16384u,  SO, SE, 1, 1, 1);
    }
    GITER(34, E, O, 0u,     SE, SO, 1, 0, 1);
    GITER(35, O, E, 16384u, SO, SE, 0, 0, 0);

#undef GITER

    // epilogue: C/D col = l15 -> P, row = lg*4+r -> o   (93312 = 729*128 exact)
    const int orow0 = ob * 128 + wr * 64;
    #pragma unroll
    for (int n = 0; n < 4; ++n) {
        uint32_t P = P0 + (uint32_t)(wc * 64 + n * 16 + l15);
        uint32_t ni = P / (uint32_t)HWOUT;
        uint32_t rm = P - ni * HWOUT;
        float* ob_ = out + (size_t)(ni * 256u + orow0) * HWOUT + rm;
        #pragma unroll
        for (int m = 0; m < 4; ++m)
            #pragma unroll
            for (int r = 0; r < 4; ++r)
                ob_[(size_t)(m * 16 + lg * 4 + r) * HWOUT] = acc[m][n][r];
    }
}

// ---- slow correct fallback (only if ws too small)
__global__ void bconv_fallback(const float* __restrict__ X, const float* __restrict__ W,
                               float* __restrict__ out) {
    size_t idx = (size_t)blockIdx.x * 256 + threadIdx.x;
    int ow = (int)(idx % 54);
    int oh = (int)((idx / 54) % 54);
    int o  = (int)((idx / 2916) % 256);
    int n  = (int)(idx / 746496);
    float s = 0.f;
    for (int c = 0; c < 256; ++c) {
        const float* xr = X + ((size_t)(n * 256 + c) * 56 + oh) * 56 + ow;
        const float* wr = W + (size_t)(o * 256 + c) * 9;
        #pragma unroll
        for (int kh = 0; kh < 3; ++kh)
            #pragma unroll
            for (int kw = 0; kw < 3; ++kw) {
                float w = wr[kh * 3 + kw];
                float x = xr[kh * 56 + kw];
                s += (w >= 0.f) ? x : -x;
            }
    }
    out[idx] = s;
}

extern "C" void kernel_launch(void* const* d_in, const int* in_sizes, int n_in,
                              void* d_out, int out_size, void* d_ws, size_t ws_size,
                              hipStream_t stream) {
    const float* X = (const float*)d_in[0];
    const float* W = (const float*)d_in[1];
    float* out = (float*)d_out;

    if (ws_size < WS_NEED) {
        bconv_fallback<<<93312, 256, 0, stream>>>(X, W, out);
        return;
    }
    unsigned short* Xt = (unsigned short*)d_ws;
    uint32_t* Wb = (uint32_t*)((char*)d_ws + WB_OFF);

    wbits_k<<<36, 256, 0, stream>>>(W, Wb);
    xxform<<<12544, 256, 0, stream>>>(X, Xt);

    bconv_gemm<<<1458, 256, 0, stream>>>(Xt, (const char*)Wb, out);
}